// Round 12
// baseline (321.431 us; speedup 1.0000x reference)
//
#include <hip/hip_runtime.h>
#include <hip/hip_bf16.h>

// Taylor attention v11: occupancy-doubled v10b. One 32-row strip per block
// (2048 blocks, heavy-first), 4 waves stride-4 K-split, TWO-ROUND LDS combine
// (16.6 KB -> 8 blocks/CU = 8 waves/SIMD; VGPR pinned 64 via launch_bounds).
// Step math identical to v10b: fp16 QK^T (32x32x16), packed-fp16 Horner poly,
// half2 regs are PV A-frag pairs (permlane32_swap), fp16 V, pk-tree Z.

typedef __attribute__((ext_vector_type(8))) short bf16x8;
typedef __attribute__((ext_vector_type(8))) _Float16 f16x8;
typedef __attribute__((ext_vector_type(2))) _Float16 h2;
typedef __attribute__((ext_vector_type(2))) __fp16 fp16x2b;
typedef __attribute__((ext_vector_type(4))) float f32x4;
typedef __attribute__((ext_vector_type(16))) float f32x16;
typedef unsigned int u32;
typedef unsigned short u16;

namespace {

constexpr int T_SEQ = 2048;
constexpr int DK    = 32;
constexpr int DV    = 64;
constexpr int NBH   = 32;

// w = ((C3*s + C2)*s + C1)*s + 1  with s = raw dot (1/sqrt(32) folded in)
constexpr float C1 = 0.17677669529663687f;   // c
constexpr float C2 = 0.015625f;              // c^2/2 (exact)
constexpr float C3 = 9.2071195e-4f;          // c^3/6

// workspace layout (bytes): Khf (fp16) 4MiB | Vthf (fp16, transposed) 8MiB
constexpr size_t KHF_OFF  = 0;
constexpr size_t VTHF_OFF = (size_t)NBH * T_SEQ * DK * 2;             //  4 MiB
constexpr size_t WS_NEED  = VTHF_OFF + (size_t)NBH * DV * T_SEQ * 2;  // 12 MiB

__device__ __forceinline__ u32 pack_hi2(float f0, float f1) {
  return (__float_as_uint(f0) >> 16) | (__float_as_uint(f1) & 0xffff0000u);
}
__device__ __forceinline__ float trunc_bf(float f) {
  return __uint_as_float(__float_as_uint(f) & 0xffff0000u);
}
__device__ __forceinline__ u16 f2h(float f) {
  union { _Float16 h; u16 u; } c;
  c.h = (_Float16)f;             // RNE
  return c.u;
}
// Swap a.lanes[32:63] <-> b.lanes[0:31].
__device__ __forceinline__ void permswap(u32& a, u32& b) {
  asm volatile("v_permlane32_swap_b32 %0, %1" : "+v"(a), "+v"(b));
}

// ---------------- pack kernel (K -> fp16; V^T -> fp16) ----------------

__global__ void pack_kv(const float* __restrict__ Kg, const float* __restrict__ Vg,
                        u16* __restrict__ Khf, u16* __restrict__ Vthf) {
  __shared__ float tile[DV][33];
  const int bid = blockIdx.x;
  const int t   = threadIdx.x;
  if (bid < 2048) {  // ---- K: elementwise fp16 convert
    size_t i = ((size_t)bid * 256 + t) * 4;
    float4 f = *(const float4*)(Kg + i);
    ushort4 h;
    h.x = f2h(f.x); h.y = f2h(f.y); h.z = f2h(f.z); h.w = f2h(f.w);
    *(ushort4*)(Khf + i) = h;
  } else {           // ---- V: transpose 32k x 64c tiles, fp16
    const int vb = bid - 2048;
    const int bh = vb >> 6;
    const int k0 = (vb & 63) * 32;
    {
      const int kl = t >> 3, c0 = (t & 7) * 8;
      const float* src = Vg + ((size_t)bh * T_SEQ + k0 + kl) * DV + c0;
      float4 a = *(const float4*)src;
      float4 b = *(const float4*)(src + 4);
      tile[c0 + 0][kl] = a.x; tile[c0 + 1][kl] = a.y;
      tile[c0 + 2][kl] = a.z; tile[c0 + 3][kl] = a.w;
      tile[c0 + 4][kl] = b.x; tile[c0 + 5][kl] = b.y;
      tile[c0 + 6][kl] = b.z; tile[c0 + 7][kl] = b.w;
    }
    __syncthreads();
    {
      const int cl = t >> 2, k8 = (t & 3) * 8;
      ushort4 h0, h1;
      h0.x = f2h(tile[cl][k8 + 0]); h0.y = f2h(tile[cl][k8 + 1]);
      h0.z = f2h(tile[cl][k8 + 2]); h0.w = f2h(tile[cl][k8 + 3]);
      h1.x = f2h(tile[cl][k8 + 4]); h1.y = f2h(tile[cl][k8 + 5]);
      h1.z = f2h(tile[cl][k8 + 6]); h1.w = f2h(tile[cl][k8 + 7]);
      size_t off = ((size_t)(bh * DV + cl)) * T_SEQ + k0 + k8;
      *(ushort4*)(Vthf + off)     = h0;
      *(ushort4*)(Vthf + off + 4) = h1;
    }
  }
}

// ---------------- main kernel (v11) ----------------

__global__ __launch_bounds__(256, 8)
void taylor_attn_v11(const float* __restrict__ Qg, const u16* __restrict__ Khf,
                     const u16* __restrict__ Vthf, float* __restrict__ Outg) {
  __shared__ __align__(16) float Sp[2 * 2048];  // 16 KB: two-round combine
  __shared__ float Zp[2 * 32];

  const int tid = threadIdx.x;
  const int l   = tid & 63;
  const int w   = tid >> 6;
  const int cq  = l & 31;
  const int hi  = l >> 5;

  // decode: 2048 blocks = 64 strips x 32 bh; heavy strips first.
  // XCD x = bid&7 always serves bh in {4x..4x+3} (K/V L2-resident).
  const int bid = blockIdx.x;
  const int s   = 63 - (bid >> 5);
  const int bh  = (bid & 7) * 4 + ((bid >> 3) & 3);
  const int q0  = s * 32;

  const u16* kq = Khf + (size_t)bh * T_SEQ * DK + (size_t)cq * DK + hi * 8;
  const u16* vq = Vthf + (size_t)bh * DV * T_SEQ + (size_t)cq * T_SEQ + hi * 8;

  const h2 C3h = {(_Float16)C3, (_Float16)C3};
  const h2 C2h = {(_Float16)C2, (_Float16)C2};
  const h2 C1h = {(_Float16)C1, (_Float16)C1};
  const h2 ONEh = {(_Float16)1.0f, (_Float16)1.0f};

  f32x16 ZERO;
#pragma unroll
  for (int r = 0; r < 16; ++r) ZERO[r] = 0.f;

  // ---- Q B-fragments, fp16 RNE
  f16x8 qf[2];
#pragma unroll
  for (int t = 0; t < 2; ++t) {
    const float* qp = Qg + ((size_t)bh * T_SEQ + q0 + cq) * DK + t * 16 + hi * 8;
    float4 a = *(const float4*)qp;
    float4 b = *(const float4*)(qp + 4);
    f16x8 v;
    v[0] = (_Float16)a.x; v[1] = (_Float16)a.y;
    v[2] = (_Float16)a.z; v[3] = (_Float16)a.w;
    v[4] = (_Float16)b.x; v[5] = (_Float16)b.y;
    v[6] = (_Float16)b.z; v[7] = (_Float16)b.w;
    qf[t] = v;
  }

  f32x16 acc0 = ZERO, acc1 = ZERO;
  float zacc = 0.f;

  auto LOADK = [&](f16x8* kf, int kt) {
    const u16* kp = kq + (size_t)kt * 1024;
    kf[0] = *(const f16x8*)kp;
    kf[1] = *(const f16x8*)(kp + 16);
  };
  auto LOADV = [&](f16x8* vf, int kt) {
#pragma unroll
    for (int ct = 0; ct < 2; ++ct)
#pragma unroll
      for (int t = 0; t < 2; ++t)
        vf[ct * 2 + t] = *(const f16x8*)(
            vq + (size_t)ct * 32 * T_SEQ + kt * 32 + t * 16);
  };
  auto STEP = [&](const f16x8* kf, const f16x8* vf, bool diag) {
    f32x16 d = __builtin_amdgcn_mfma_f32_32x32x16_f16(kf[0], qf[0], ZERO, 0, 0, 0);
    d = __builtin_amdgcn_mfma_f32_32x32x16_f16(kf[1], qf[1], d, 0, 0, 0);

    union cvu { fp16x2b p; h2 h; u32 u; };
    cvu wv[8];
#pragma unroll
    for (int j = 0; j < 8; ++j) {
      cvu c;
      c.p = __builtin_amdgcn_cvt_pkrtz(d[2 * j], d[2 * j + 1]);
      h2 sc = c.h;
      h2 t_ = sc * C3h + C2h;
      t_    = sc * t_ + C1h;
      wv[j].h = sc * t_ + ONEh;
    }
    if (diag) {
#pragma unroll
      for (int j = 0; j < 8; ++j) {
        const int r0  = 2 * j;
        const int kre = (r0 & 3) + 8 * (r0 >> 2) + 4 * hi;
        u32 msk = ((kre <= cq) ? 0xffffu : 0u) |
                  ((kre + 1 <= cq) ? 0xffff0000u : 0u);
        wv[j].u &= msk;
      }
    }
    {
      h2 zs = ((wv[0].h + wv[1].h) + (wv[2].h + wv[3].h)) +
              ((wv[4].h + wv[5].h) + (wv[6].h + wv[7].h));
      zacc += (float)zs[0] + (float)zs[1];
    }
    union { f16x8 v; u32 u[4]; } WH[2];
#pragma unroll
    for (int t = 0; t < 2; ++t) {
      u32 p0 = wv[4 * t + 0].u, p1 = wv[4 * t + 1].u;
      u32 p2 = wv[4 * t + 2].u, p3 = wv[4 * t + 3].u;
      permswap(p0, p2); permswap(p1, p3);
      WH[t].u[0] = p0; WH[t].u[1] = p1; WH[t].u[2] = p2; WH[t].u[3] = p3;
    }
    acc0 = __builtin_amdgcn_mfma_f32_32x32x16_f16(WH[0].v, vf[0], acc0, 0, 0, 0);
    acc0 = __builtin_amdgcn_mfma_f32_32x32x16_f16(WH[1].v, vf[1], acc0, 0, 0, 0);
    acc1 = __builtin_amdgcn_mfma_f32_32x32x16_f16(WH[0].v, vf[2], acc1, 0, 0, 0);
    acc1 = __builtin_amdgcn_mfma_f32_32x32x16_f16(WH[1].v, vf[3], acc1, 0, 0, 0);
  };

  // ---- pipelined main loop (kt < s, mask-free): K double-buffered, V early
  {
    int kt = w;
    if (kt < s) {
      f16x8 kA[2], kB[2];
      LOADK(kA, kt);
      while (true) {
        int kn = kt + 4;
        if (kn < s) {
          LOADK(kB, kn);
          f16x8 vf[4]; LOADV(vf, kt);
          STEP(kA, vf, false);
          kt = kn;
        } else {
          f16x8 vf[4]; LOADV(vf, kt);
          STEP(kA, vf, false);
          break;
        }
        kn = kt + 4;
        if (kn < s) {
          LOADK(kA, kn);
          f16x8 vf[4]; LOADV(vf, kt);
          STEP(kB, vf, false);
          kt = kn;
        } else {
          f16x8 vf[4]; LOADV(vf, kt);
          STEP(kB, vf, false);
          break;
        }
      }
    }
  }
  // ---- peeled diagonal step (owner wave only, masked)
  if ((s & 3) == w) {
    f16x8 kD[2]; LOADK(kD, s);
    f16x8 vD[4]; LOADV(vD, s);
    STEP(kD, vD, true);
  }

  // ---- Z fold across lane halves (lane l, l^32 share q=cq)
  float zt = zacc + __shfl_xor(zacc, 32);

  // ---- two-round combine ----
  // Round 1: waves 2,3 publish partials into slice (w-2).
  if (w >= 2) {
    if (hi == 0) Zp[(w - 2) * 32 + cq] = zt;
#pragma unroll
    for (int r = 0; r < 16; ++r) {
      const int qr = (r & 3) + 8 * (r >> 2) + 4 * hi;
      Sp[(w - 2) * 2048 + qr * 64 + cq]      = acc0[r];
      Sp[(w - 2) * 2048 + qr * 64 + 32 + cq] = acc1[r];
    }
  }
  __syncthreads();
  // Round 2: waves 0,1 fold partner slice into acc, republish combined.
  if (w < 2) {
    zt += Zp[w * 32 + cq];
#pragma unroll
    for (int r = 0; r < 16; ++r) {
      const int qr = (r & 3) + 8 * (r >> 2) + 4 * hi;
      acc0[r] += Sp[w * 2048 + qr * 64 + cq];
      acc1[r] += Sp[w * 2048 + qr * 64 + 32 + cq];
    }
    if (hi == 0) Zp[w * 32 + cq] = zt;
#pragma unroll
    for (int r = 0; r < 16; ++r) {
      const int qr = (r & 3) + 8 * (r >> 2) + 4 * hi;
      Sp[w * 2048 + qr * 64 + cq]      = acc0[r];
      Sp[w * 2048 + qr * 64 + 32 + cq] = acc1[r];
    }
  }
  __syncthreads();

  // ---- final: sum 2 slices + divide + store (2 float4 per thread)
  const f32x4* S4 = (const f32x4*)Sp;
#pragma unroll
  for (int i = 0; i < 2; ++i) {
    const int e4  = tid + i * 256;
    const int row = e4 >> 4;
    f32x4 ssum = S4[e4] + S4[512 + e4];
    float z = Zp[row] + Zp[32 + row];
    float inv = 1.0f / z;
    float4 o;
    o.x = ssum[0] * inv; o.y = ssum[1] * inv;
    o.z = ssum[2] * inv; o.w = ssum[3] * inv;
    *(float4*)(Outg + ((size_t)bh * T_SEQ + q0 + row) * DV + (e4 & 15) * 4) = o;
  }
}

// ---------------- fallback (no workspace): v2 staged-LDS kernel ----------------

constexpr int QT_FB = 64;
constexpr int KT_FB = 32;
constexpr int LDSW  = 40;
constexpr float SCALE = 0.17677669529663687f;

__global__ __launch_bounds__(256, 4)
void taylor_attn_fb(const float* __restrict__ Qg, const float* __restrict__ Kg,
                    const float* __restrict__ Vg, float* __restrict__ Outg) {
  __shared__ __align__(16) unsigned short Qhi[QT_FB * LDSW], Qlo[QT_FB * LDSW];
  __shared__ __align__(16) unsigned short Khi_[KT_FB * LDSW], Klo_[KT_FB * LDSW];
  __shared__ __align__(16) unsigned short Vthi_[DV * LDSW], Vtlo_[DV * LDSW];
  __shared__ __align__(16) unsigned Wp[4][16 * 32];

  const int tid  = threadIdx.x;
  const int lane = tid & 63;
  const int wid  = tid >> 6;
  const int m    = lane & 15;
  const int g    = lane >> 4;

  const int bid = blockIdx.x;
  const int v   = bid >> 3;
  const int bh  = (bid & 7) * 4 + (v >> 5);
  const int qt  = 31 - (v & 31);
  const int q0  = qt * QT_FB;

  const float* Qbase = Qg + ((size_t)bh * T_SEQ + q0) * DK;
  const float* Kbase = Kg + (size_t)bh * T_SEQ * DK;
  const float* Vbase = Vg + (size_t)bh * T_SEQ * DV;

#pragma unroll
  for (int p = 0; p < 2; ++p) {
    int e = tid + p * 256, row = e >> 3, c4 = (e & 7) * 4;
    float4 f = *(const float4*)(Qbase + row * DK + c4);
    uint2 h, l;
    h.x = pack_hi2(f.x, f.y); h.y = pack_hi2(f.z, f.w);
    l.x = pack_hi2(f.x - trunc_bf(f.x), f.y - trunc_bf(f.y));
    l.y = pack_hi2(f.z - trunc_bf(f.z), f.w - trunc_bf(f.w));
    *(uint2*)&Qhi[row * LDSW + c4] = h;
    *(uint2*)&Qlo[row * LDSW + c4] = l;
  }
  __syncthreads();

  const int wq = wid * 16;
  const bf16x8 qhi = *(const bf16x8*)&Qhi[(wq + m) * LDSW + g * 8];
  const bf16x8 qlo = *(const bf16x8*)&Qlo[(wq + m) * LDSW + g * 8];

  f32x4 acc[4];
#pragma unroll
  for (int ct = 0; ct < 4; ++ct) acc[ct] = f32x4{0.f, 0.f, 0.f, 0.f};
  float zacc[4] = {0.f, 0.f, 0.f, 0.f};

  const int q_lane0 = q0 + wq + g * 4;
  const int q_wave_max = q0 + wq + 15;

  const int nkt = (q0 + QT_FB) / KT_FB;
  for (int kt = 0; kt < nkt; ++kt) {
    const int k0 = kt * KT_FB;
    __syncthreads();
    {
      int row = tid >> 3, c4 = (tid & 7) * 4;
      float4 f = *(const float4*)(Kbase + (size_t)(k0 + row) * DK + c4);
      uint2 h, l;
      h.x = pack_hi2(f.x, f.y); h.y = pack_hi2(f.z, f.w);
      l.x = pack_hi2(f.x - trunc_bf(f.x), f.y - trunc_bf(f.y));
      l.y = pack_hi2(f.z - trunc_bf(f.z), f.w - trunc_bf(f.w));
      *(uint2*)&Khi_[row * LDSW + c4] = h;
      *(uint2*)&Klo_[row * LDSW + c4] = l;
    }
    {
      int kk = (tid & 15) * 2, c4 = (tid >> 4) * 4;
      const float* vp = Vbase + (size_t)(k0 + kk) * DV + c4;
      float4 a = *(const float4*)vp;
      float4 b = *(const float4*)(vp + DV);
      float af[4] = {a.x, a.y, a.z, a.w};
      float bf_[4] = {b.x, b.y, b.z, b.w};
#pragma unroll
      for (int jj = 0; jj < 4; ++jj) {
        *(unsigned*)&Vthi_[(c4 + jj) * LDSW + kk] = pack_hi2(af[jj], bf_[jj]);
        *(unsigned*)&Vtlo_[(c4 + jj) * LDSW + kk] =
            pack_hi2(af[jj] - trunc_bf(af[jj]), bf_[jj] - trunc_bf(bf_[jj]));
      }
    }
    __syncthreads();

    if (k0 > q_wave_max) continue;

#pragma unroll
    for (int k16 = 0; k16 < 2; ++k16) {
      const int kcol0 = k16 * 16;
      bf16x8 khi = *(const bf16x8*)&Khi_[(kcol0 + m) * LDSW + g * 8];
      bf16x8 klo = *(const bf16x8*)&Klo_[(kcol0 + m) * LDSW + g * 8];
      f32x4 sc = {0.f, 0.f, 0.f, 0.f};
      sc = __builtin_amdgcn_mfma_f32_16x16x32_bf16(qhi, khi, sc, 0, 0, 0);
      sc = __builtin_amdgcn_mfma_f32_16x16x32_bf16(qhi, klo, sc, 0, 0, 0);
      sc = __builtin_amdgcn_mfma_f32_16x16x32_bf16(qlo, khi, sc, 0, 0, 0);
      const int k_abs = k0 + kcol0 + m;
      const int kcol  = kcol0 + m;
#pragma unroll
      for (int r = 0; r < 4; ++r) {
        float x  = sc[r] * SCALE;
        float a3 = __builtin_fmaf(x, 0.3333333333333333f, 1.0f);
        float a2 = __builtin_fmaf(x * 0.5f, a3, 1.0f);
        float wvv = __builtin_fmaf(x, a2, 1.0f);
        wvv = (k_abs <= q_lane0 + r) ? wvv : 0.0f;
        zacc[r] += wvv;
        float wl = wvv - trunc_bf(wvv);
        unsigned packed = (__float_as_uint(wvv) >> 16) |
                          (__float_as_uint(wl) & 0xffff0000u);
        const int q = g * 4 + r;
        Wp[wid][q * 32 + (((kcol >> 2) ^ (q & 7)) << 2) + (kcol & 3)] = packed;
      }
    }

    uint4 pa = *(const uint4*)&Wp[wid][m * 32 + (((2 * g) ^ (m & 7)) << 2)];
    uint4 pb = *(const uint4*)&Wp[wid][m * 32 + (((2 * g + 1) ^ (m & 7)) << 2)];
    union { bf16x8 v; unsigned u[4]; } WH, WL;
    WH.u[0] = (pa.x & 0xffffu) | (pa.y << 16);
    WH.u[1] = (pa.z & 0xffffu) | (pa.w << 16);
    WH.u[2] = (pb.x & 0xffffu) | (pb.y << 16);
    WH.u[3] = (pb.z & 0xffffu) | (pb.w << 16);
    WL.u[0] = (pa.x >> 16) | (pa.y & 0xffff0000u);
    WL.u[1] = (pa.z >> 16) | (pa.w & 0xffff0000u);
    WL.u[2] = (pb.x >> 16) | (pb.y & 0xffff0000u);
    WL.u[3] = (pb.z >> 16) | (pb.w & 0xffff0000u);

#pragma unroll
    for (int ct = 0; ct < 4; ++ct) {
      bf16x8 vhi = *(const bf16x8*)&Vthi_[(ct * 16 + m) * LDSW + g * 8];
      bf16x8 vlo = *(const bf16x8*)&Vtlo_[(ct * 16 + m) * LDSW + g * 8];
      acc[ct] = __builtin_amdgcn_mfma_f32_16x16x32_bf16(WH.v, vhi, acc[ct], 0, 0, 0);
      acc[ct] = __builtin_amdgcn_mfma_f32_16x16x32_bf16(WH.v, vlo, acc[ct], 0, 0, 0);
      acc[ct] = __builtin_amdgcn_mfma_f32_16x16x32_bf16(WL.v, vhi, acc[ct], 0, 0, 0);
    }
  }

  float invz[4];
#pragma unroll
  for (int r = 0; r < 4; ++r) {
    float z = zacc[r];
    z += __shfl_xor(z, 1); z += __shfl_xor(z, 2);
    z += __shfl_xor(z, 4); z += __shfl_xor(z, 8);
    invz[r] = 1.0f / z;
  }

  float* ob = Outg + ((size_t)bh * T_SEQ + (q0 + wq)) * DV;
#pragma unroll
  for (int ct = 0; ct < 4; ++ct)
#pragma unroll
    for (int r = 0; r < 4; ++r)
      ob[(g * 4 + r) * DV + ct * 16 + m] = acc[ct][r] * invz[r];
}

}  // namespace

extern "C" void kernel_launch(void* const* d_in, const int* in_sizes, int n_in,
                              void* d_out, int out_size, void* d_ws, size_t ws_size,
                              hipStream_t stream) {
  const float* Q = (const float*)d_in[0];
  const float* K = (const float*)d_in[1];
  const float* V = (const float*)d_in[2];
  float* Out = (float*)d_out;

  if (ws_size >= WS_NEED && d_ws != nullptr) {
    u16* khf  = (u16*)((char*)d_ws + KHF_OFF);
    u16* vthf = (u16*)((char*)d_ws + VTHF_OFF);

    hipLaunchKernelGGL(pack_kv, dim3(4096), dim3(256), 0, stream, K, V, khf, vthf);
    hipLaunchKernelGGL(taylor_attn_v11, dim3(2048), dim3(256), 0, stream,
                       Q, khf, vthf, Out);
  } else {
    hipLaunchKernelGGL(taylor_attn_fb, dim3(1024), dim3(256), 0, stream,
                       Q, K, V, Out);
  }
}

// Round 13
// 93.615 us; speedup vs baseline: 3.4335x; 3.4335x over previous
//
#include <hip/hip_runtime.h>
#include <hip/hip_bf16.h>

// Taylor attention v12: v11 (one strip/block, 2048 blocks heavy-first, 4 waves
// stride-4 K-split, two-round 16.6KB LDS combine) with the register budget
// fixed: __launch_bounds__(256,6) -> 85-VGPR cap, natural usage ~64, no spill.
// Runtime occupancy: LDS 16.9KB allows 9 blocks/CU, VGPR 64 allows 8 -> 8
// blocks/CU = 8 waves/SIMD (double v10b) WITHOUT allocator starvation.
// Step math identical to v10b/v11: fp16 QK^T (32x32x16), packed-fp16 Horner,
// half2 regs are PV A-frag pairs (permlane32_swap), fp16 V, pk-tree Z.

typedef __attribute__((ext_vector_type(8))) short bf16x8;
typedef __attribute__((ext_vector_type(8))) _Float16 f16x8;
typedef __attribute__((ext_vector_type(2))) _Float16 h2;
typedef __attribute__((ext_vector_type(2))) __fp16 fp16x2b;
typedef __attribute__((ext_vector_type(4))) float f32x4;
typedef __attribute__((ext_vector_type(16))) float f32x16;
typedef unsigned int u32;
typedef unsigned short u16;

namespace {

constexpr int T_SEQ = 2048;
constexpr int DK    = 32;
constexpr int DV    = 64;
constexpr int NBH   = 32;

// w = ((C3*s + C2)*s + C1)*s + 1  with s = raw dot (1/sqrt(32) folded in)
constexpr float C1 = 0.17677669529663687f;   // c
constexpr float C2 = 0.015625f;              // c^2/2 (exact)
constexpr float C3 = 9.2071195e-4f;          // c^3/6

// workspace layout (bytes): Khf (fp16) 4MiB | Vthf (fp16, transposed) 8MiB
constexpr size_t KHF_OFF  = 0;
constexpr size_t VTHF_OFF = (size_t)NBH * T_SEQ * DK * 2;             //  4 MiB
constexpr size_t WS_NEED  = VTHF_OFF + (size_t)NBH * DV * T_SEQ * 2;  // 12 MiB

__device__ __forceinline__ u32 pack_hi2(float f0, float f1) {
  return (__float_as_uint(f0) >> 16) | (__float_as_uint(f1) & 0xffff0000u);
}
__device__ __forceinline__ float trunc_bf(float f) {
  return __uint_as_float(__float_as_uint(f) & 0xffff0000u);
}
__device__ __forceinline__ u16 f2h(float f) {
  union { _Float16 h; u16 u; } c;
  c.h = (_Float16)f;             // RNE
  return c.u;
}
// Swap a.lanes[32:63] <-> b.lanes[0:31].
__device__ __forceinline__ void permswap(u32& a, u32& b) {
  asm volatile("v_permlane32_swap_b32 %0, %1" : "+v"(a), "+v"(b));
}

// ---------------- pack kernel (K -> fp16; V^T -> fp16) ----------------

__global__ void pack_kv(const float* __restrict__ Kg, const float* __restrict__ Vg,
                        u16* __restrict__ Khf, u16* __restrict__ Vthf) {
  __shared__ float tile[DV][33];
  const int bid = blockIdx.x;
  const int t   = threadIdx.x;
  if (bid < 2048) {  // ---- K: elementwise fp16 convert
    size_t i = ((size_t)bid * 256 + t) * 4;
    float4 f = *(const float4*)(Kg + i);
    ushort4 h;
    h.x = f2h(f.x); h.y = f2h(f.y); h.z = f2h(f.z); h.w = f2h(f.w);
    *(ushort4*)(Khf + i) = h;
  } else {           // ---- V: transpose 32k x 64c tiles, fp16
    const int vb = bid - 2048;
    const int bh = vb >> 6;
    const int k0 = (vb & 63) * 32;
    {
      const int kl = t >> 3, c0 = (t & 7) * 8;
      const float* src = Vg + ((size_t)bh * T_SEQ + k0 + kl) * DV + c0;
      float4 a = *(const float4*)src;
      float4 b = *(const float4*)(src + 4);
      tile[c0 + 0][kl] = a.x; tile[c0 + 1][kl] = a.y;
      tile[c0 + 2][kl] = a.z; tile[c0 + 3][kl] = a.w;
      tile[c0 + 4][kl] = b.x; tile[c0 + 5][kl] = b.y;
      tile[c0 + 6][kl] = b.z; tile[c0 + 7][kl] = b.w;
    }
    __syncthreads();
    {
      const int cl = t >> 2, k8 = (t & 3) * 8;
      ushort4 h0, h1;
      h0.x = f2h(tile[cl][k8 + 0]); h0.y = f2h(tile[cl][k8 + 1]);
      h0.z = f2h(tile[cl][k8 + 2]); h0.w = f2h(tile[cl][k8 + 3]);
      h1.x = f2h(tile[cl][k8 + 4]); h1.y = f2h(tile[cl][k8 + 5]);
      h1.z = f2h(tile[cl][k8 + 6]); h1.w = f2h(tile[cl][k8 + 7]);
      size_t off = ((size_t)(bh * DV + cl)) * T_SEQ + k0 + k8;
      *(ushort4*)(Vthf + off)     = h0;
      *(ushort4*)(Vthf + off + 4) = h1;
    }
  }
}

// ---------------- main kernel (v12) ----------------

__global__ __launch_bounds__(256, 6)
void taylor_attn_v12(const float* __restrict__ Qg, const u16* __restrict__ Khf,
                     const u16* __restrict__ Vthf, float* __restrict__ Outg) {
  __shared__ __align__(16) float Sp[2 * 2048];  // 16 KB: two-round combine
  __shared__ float Zp[2 * 32];

  const int tid = threadIdx.x;
  const int l   = tid & 63;
  const int w   = tid >> 6;
  const int cq  = l & 31;
  const int hi  = l >> 5;

  // decode: 2048 blocks = 64 strips x 32 bh; heavy strips first.
  // XCD x = bid&7 always serves bh in {4x..4x+3} (K/V L2-resident).
  const int bid = blockIdx.x;
  const int s   = 63 - (bid >> 5);
  const int bh  = (bid & 7) * 4 + ((bid >> 3) & 3);
  const int q0  = s * 32;

  const u16* kq = Khf + (size_t)bh * T_SEQ * DK + (size_t)cq * DK + hi * 8;
  const u16* vq = Vthf + (size_t)bh * DV * T_SEQ + (size_t)cq * T_SEQ + hi * 8;

  const h2 C3h = {(_Float16)C3, (_Float16)C3};
  const h2 C2h = {(_Float16)C2, (_Float16)C2};
  const h2 C1h = {(_Float16)C1, (_Float16)C1};
  const h2 ONEh = {(_Float16)1.0f, (_Float16)1.0f};

  f32x16 ZERO;
#pragma unroll
  for (int r = 0; r < 16; ++r) ZERO[r] = 0.f;

  // ---- Q B-fragments, fp16 RNE
  f16x8 qf[2];
#pragma unroll
  for (int t = 0; t < 2; ++t) {
    const float* qp = Qg + ((size_t)bh * T_SEQ + q0 + cq) * DK + t * 16 + hi * 8;
    float4 a = *(const float4*)qp;
    float4 b = *(const float4*)(qp + 4);
    f16x8 v;
    v[0] = (_Float16)a.x; v[1] = (_Float16)a.y;
    v[2] = (_Float16)a.z; v[3] = (_Float16)a.w;
    v[4] = (_Float16)b.x; v[5] = (_Float16)b.y;
    v[6] = (_Float16)b.z; v[7] = (_Float16)b.w;
    qf[t] = v;
  }

  f32x16 acc0 = ZERO, acc1 = ZERO;
  float zacc = 0.f;

  auto LOADK = [&](f16x8* kf, int kt) {
    const u16* kp = kq + (size_t)kt * 1024;
    kf[0] = *(const f16x8*)kp;
    kf[1] = *(const f16x8*)(kp + 16);
  };
  auto LOADV = [&](f16x8* vf, int kt) {
#pragma unroll
    for (int ct = 0; ct < 2; ++ct)
#pragma unroll
      for (int t = 0; t < 2; ++t)
        vf[ct * 2 + t] = *(const f16x8*)(
            vq + (size_t)ct * 32 * T_SEQ + kt * 32 + t * 16);
  };
  auto STEP = [&](const f16x8* kf, const f16x8* vf, bool diag) {
    f32x16 d = __builtin_amdgcn_mfma_f32_32x32x16_f16(kf[0], qf[0], ZERO, 0, 0, 0);
    d = __builtin_amdgcn_mfma_f32_32x32x16_f16(kf[1], qf[1], d, 0, 0, 0);

    union cvu { fp16x2b p; h2 h; u32 u; };
    cvu wv[8];
#pragma unroll
    for (int j = 0; j < 8; ++j) {
      cvu c;
      c.p = __builtin_amdgcn_cvt_pkrtz(d[2 * j], d[2 * j + 1]);
      h2 sc = c.h;
      h2 t_ = sc * C3h + C2h;
      t_    = sc * t_ + C1h;
      wv[j].h = sc * t_ + ONEh;
    }
    if (diag) {
#pragma unroll
      for (int j = 0; j < 8; ++j) {
        const int r0  = 2 * j;
        const int kre = (r0 & 3) + 8 * (r0 >> 2) + 4 * hi;
        u32 msk = ((kre <= cq) ? 0xffffu : 0u) |
                  ((kre + 1 <= cq) ? 0xffff0000u : 0u);
        wv[j].u &= msk;
      }
    }
    {
      h2 zs = ((wv[0].h + wv[1].h) + (wv[2].h + wv[3].h)) +
              ((wv[4].h + wv[5].h) + (wv[6].h + wv[7].h));
      zacc += (float)zs[0] + (float)zs[1];
    }
    union { f16x8 v; u32 u[4]; } WH[2];
#pragma unroll
    for (int t = 0; t < 2; ++t) {
      u32 p0 = wv[4 * t + 0].u, p1 = wv[4 * t + 1].u;
      u32 p2 = wv[4 * t + 2].u, p3 = wv[4 * t + 3].u;
      permswap(p0, p2); permswap(p1, p3);
      WH[t].u[0] = p0; WH[t].u[1] = p1; WH[t].u[2] = p2; WH[t].u[3] = p3;
    }
    acc0 = __builtin_amdgcn_mfma_f32_32x32x16_f16(WH[0].v, vf[0], acc0, 0, 0, 0);
    acc0 = __builtin_amdgcn_mfma_f32_32x32x16_f16(WH[1].v, vf[1], acc0, 0, 0, 0);
    acc1 = __builtin_amdgcn_mfma_f32_32x32x16_f16(WH[0].v, vf[2], acc1, 0, 0, 0);
    acc1 = __builtin_amdgcn_mfma_f32_32x32x16_f16(WH[1].v, vf[3], acc1, 0, 0, 0);
  };

  // ---- pipelined main loop (kt < s, mask-free): K double-buffered, V early
  {
    int kt = w;
    if (kt < s) {
      f16x8 kA[2], kB[2];
      LOADK(kA, kt);
      while (true) {
        int kn = kt + 4;
        if (kn < s) {
          LOADK(kB, kn);
          f16x8 vf[4]; LOADV(vf, kt);
          STEP(kA, vf, false);
          kt = kn;
        } else {
          f16x8 vf[4]; LOADV(vf, kt);
          STEP(kA, vf, false);
          break;
        }
        kn = kt + 4;
        if (kn < s) {
          LOADK(kA, kn);
          f16x8 vf[4]; LOADV(vf, kt);
          STEP(kB, vf, false);
          kt = kn;
        } else {
          f16x8 vf[4]; LOADV(vf, kt);
          STEP(kB, vf, false);
          break;
        }
      }
    }
  }
  // ---- peeled diagonal step (owner wave only, masked)
  if ((s & 3) == w) {
    f16x8 kD[2]; LOADK(kD, s);
    f16x8 vD[4]; LOADV(vD, s);
    STEP(kD, vD, true);
  }

  // ---- Z fold across lane halves (lane l, l^32 share q=cq)
  float zt = zacc + __shfl_xor(zacc, 32);

  // ---- two-round combine ----
  // Round 1: waves 2,3 publish partials into slice (w-2).
  if (w >= 2) {
    if (hi == 0) Zp[(w - 2) * 32 + cq] = zt;
#pragma unroll
    for (int r = 0; r < 16; ++r) {
      const int qr = (r & 3) + 8 * (r >> 2) + 4 * hi;
      Sp[(w - 2) * 2048 + qr * 64 + cq]      = acc0[r];
      Sp[(w - 2) * 2048 + qr * 64 + 32 + cq] = acc1[r];
    }
  }
  __syncthreads();
  // Round 2: waves 0,1 fold partner slice into acc, republish combined.
  if (w < 2) {
    zt += Zp[w * 32 + cq];
#pragma unroll
    for (int r = 0; r < 16; ++r) {
      const int qr = (r & 3) + 8 * (r >> 2) + 4 * hi;
      acc0[r] += Sp[w * 2048 + qr * 64 + cq];
      acc1[r] += Sp[w * 2048 + qr * 64 + 32 + cq];
    }
    if (hi == 0) Zp[w * 32 + cq] = zt;
#pragma unroll
    for (int r = 0; r < 16; ++r) {
      const int qr = (r & 3) + 8 * (r >> 2) + 4 * hi;
      Sp[w * 2048 + qr * 64 + cq]      = acc0[r];
      Sp[w * 2048 + qr * 64 + 32 + cq] = acc1[r];
    }
  }
  __syncthreads();

  // ---- final: sum 2 slices + divide + store (2 float4 per thread)
  const f32x4* S4 = (const f32x4*)Sp;
#pragma unroll
  for (int i = 0; i < 2; ++i) {
    const int e4  = tid + i * 256;
    const int row = e4 >> 4;
    f32x4 ssum = S4[e4] + S4[512 + e4];
    float z = Zp[row] + Zp[32 + row];
    float inv = 1.0f / z;
    float4 o;
    o.x = ssum[0] * inv; o.y = ssum[1] * inv;
    o.z = ssum[2] * inv; o.w = ssum[3] * inv;
    *(float4*)(Outg + ((size_t)bh * T_SEQ + q0 + row) * DV + (e4 & 15) * 4) = o;
  }
}

// ---------------- fallback (no workspace): v2 staged-LDS kernel ----------------

constexpr int QT_FB = 64;
constexpr int KT_FB = 32;
constexpr int LDSW  = 40;
constexpr float SCALE = 0.17677669529663687f;

__global__ __launch_bounds__(256, 4)
void taylor_attn_fb(const float* __restrict__ Qg, const float* __restrict__ Kg,
                    const float* __restrict__ Vg, float* __restrict__ Outg) {
  __shared__ __align__(16) unsigned short Qhi[QT_FB * LDSW], Qlo[QT_FB * LDSW];
  __shared__ __align__(16) unsigned short Khi_[KT_FB * LDSW], Klo_[KT_FB * LDSW];
  __shared__ __align__(16) unsigned short Vthi_[DV * LDSW], Vtlo_[DV * LDSW];
  __shared__ __align__(16) unsigned Wp[4][16 * 32];

  const int tid  = threadIdx.x;
  const int lane = tid & 63;
  const int wid  = tid >> 6;
  const int m    = lane & 15;
  const int g    = lane >> 4;

  const int bid = blockIdx.x;
  const int v   = bid >> 3;
  const int bh  = (bid & 7) * 4 + (v >> 5);
  const int qt  = 31 - (v & 31);
  const int q0  = qt * QT_FB;

  const float* Qbase = Qg + ((size_t)bh * T_SEQ + q0) * DK;
  const float* Kbase = Kg + (size_t)bh * T_SEQ * DK;
  const float* Vbase = Vg + (size_t)bh * T_SEQ * DV;

#pragma unroll
  for (int p = 0; p < 2; ++p) {
    int e = tid + p * 256, row = e >> 3, c4 = (e & 7) * 4;
    float4 f = *(const float4*)(Qbase + row * DK + c4);
    uint2 h, l;
    h.x = pack_hi2(f.x, f.y); h.y = pack_hi2(f.z, f.w);
    l.x = pack_hi2(f.x - trunc_bf(f.x), f.y - trunc_bf(f.y));
    l.y = pack_hi2(f.z - trunc_bf(f.z), f.w - trunc_bf(f.w));
    *(uint2*)&Qhi[row * LDSW + c4] = h;
    *(uint2*)&Qlo[row * LDSW + c4] = l;
  }
  __syncthreads();

  const int wq = wid * 16;
  const bf16x8 qhi = *(const bf16x8*)&Qhi[(wq + m) * LDSW + g * 8];
  const bf16x8 qlo = *(const bf16x8*)&Qlo[(wq + m) * LDSW + g * 8];

  f32x4 acc[4];
#pragma unroll
  for (int ct = 0; ct < 4; ++ct) acc[ct] = f32x4{0.f, 0.f, 0.f, 0.f};
  float zacc[4] = {0.f, 0.f, 0.f, 0.f};

  const int q_lane0 = q0 + wq + g * 4;
  const int q_wave_max = q0 + wq + 15;

  const int nkt = (q0 + QT_FB) / KT_FB;
  for (int kt = 0; kt < nkt; ++kt) {
    const int k0 = kt * KT_FB;
    __syncthreads();
    {
      int row = tid >> 3, c4 = (tid & 7) * 4;
      float4 f = *(const float4*)(Kbase + (size_t)(k0 + row) * DK + c4);
      uint2 h, l;
      h.x = pack_hi2(f.x, f.y); h.y = pack_hi2(f.z, f.w);
      l.x = pack_hi2(f.x - trunc_bf(f.x), f.y - trunc_bf(f.y));
      l.y = pack_hi2(f.z - trunc_bf(f.z), f.w - trunc_bf(f.w));
      *(uint2*)&Khi_[row * LDSW + c4] = h;
      *(uint2*)&Klo_[row * LDSW + c4] = l;
    }
    {
      int kk = (tid & 15) * 2, c4 = (tid >> 4) * 4;
      const float* vp = Vbase + (size_t)(k0 + kk) * DV + c4;
      float4 a = *(const float4*)vp;
      float4 b = *(const float4*)(vp + DV);
      float af[4] = {a.x, a.y, a.z, a.w};
      float bf_[4] = {b.x, b.y, b.z, b.w};
#pragma unroll
      for (int jj = 0; jj < 4; ++jj) {
        *(unsigned*)&Vthi_[(c4 + jj) * LDSW + kk] = pack_hi2(af[jj], bf_[jj]);
        *(unsigned*)&Vtlo_[(c4 + jj) * LDSW + kk] =
            pack_hi2(af[jj] - trunc_bf(af[jj]), bf_[jj] - trunc_bf(bf_[jj]));
      }
    }
    __syncthreads();

    if (k0 > q_wave_max) continue;

#pragma unroll
    for (int k16 = 0; k16 < 2; ++k16) {
      const int kcol0 = k16 * 16;
      bf16x8 khi = *(const bf16x8*)&Khi_[(kcol0 + m) * LDSW + g * 8];
      bf16x8 klo = *(const bf16x8*)&Klo_[(kcol0 + m) * LDSW + g * 8];
      f32x4 sc = {0.f, 0.f, 0.f, 0.f};
      sc = __builtin_amdgcn_mfma_f32_16x16x32_bf16(qhi, khi, sc, 0, 0, 0);
      sc = __builtin_amdgcn_mfma_f32_16x16x32_bf16(qhi, klo, sc, 0, 0, 0);
      sc = __builtin_amdgcn_mfma_f32_16x16x32_bf16(qlo, khi, sc, 0, 0, 0);
      const int k_abs = k0 + kcol0 + m;
      const int kcol  = kcol0 + m;
#pragma unroll
      for (int r = 0; r < 4; ++r) {
        float x  = sc[r] * SCALE;
        float a3 = __builtin_fmaf(x, 0.3333333333333333f, 1.0f);
        float a2 = __builtin_fmaf(x * 0.5f, a3, 1.0f);
        float wvv = __builtin_fmaf(x, a2, 1.0f);
        wvv = (k_abs <= q_lane0 + r) ? wvv : 0.0f;
        zacc[r] += wvv;
        float wl = wvv - trunc_bf(wvv);
        unsigned packed = (__float_as_uint(wvv) >> 16) |
                          (__float_as_uint(wl) & 0xffff0000u);
        const int q = g * 4 + r;
        Wp[wid][q * 32 + (((kcol >> 2) ^ (q & 7)) << 2) + (kcol & 3)] = packed;
      }
    }

    uint4 pa = *(const uint4*)&Wp[wid][m * 32 + (((2 * g) ^ (m & 7)) << 2)];
    uint4 pb = *(const uint4*)&Wp[wid][m * 32 + (((2 * g + 1) ^ (m & 7)) << 2)];
    union { bf16x8 v; unsigned u[4]; } WH, WL;
    WH.u[0] = (pa.x & 0xffffu) | (pa.y << 16);
    WH.u[1] = (pa.z & 0xffffu) | (pa.w << 16);
    WH.u[2] = (pb.x & 0xffffu) | (pb.y << 16);
    WH.u[3] = (pb.z & 0xffffu) | (pb.w << 16);
    WL.u[0] = (pa.x >> 16) | (pa.y & 0xffff0000u);
    WL.u[1] = (pa.z >> 16) | (pa.w & 0xffff0000u);
    WL.u[2] = (pb.x >> 16) | (pb.y & 0xffff0000u);
    WL.u[3] = (pb.z >> 16) | (pb.w & 0xffff0000u);

#pragma unroll
    for (int ct = 0; ct < 4; ++ct) {
      bf16x8 vhi = *(const bf16x8*)&Vthi_[(ct * 16 + m) * LDSW + g * 8];
      bf16x8 vlo = *(const bf16x8*)&Vtlo_[(ct * 16 + m) * LDSW + g * 8];
      acc[ct] = __builtin_amdgcn_mfma_f32_16x16x32_bf16(WH.v, vhi, acc[ct], 0, 0, 0);
      acc[ct] = __builtin_amdgcn_mfma_f32_16x16x32_bf16(WH.v, vlo, acc[ct], 0, 0, 0);
      acc[ct] = __builtin_amdgcn_mfma_f32_16x16x32_bf16(WL.v, vhi, acc[ct], 0, 0, 0);
    }
  }

  float invz[4];
#pragma unroll
  for (int r = 0; r < 4; ++r) {
    float z = zacc[r];
    z += __shfl_xor(z, 1); z += __shfl_xor(z, 2);
    z += __shfl_xor(z, 4); z += __shfl_xor(z, 8);
    invz[r] = 1.0f / z;
  }

  float* ob = Outg + ((size_t)bh * T_SEQ + (q0 + wq)) * DV;
#pragma unroll
  for (int ct = 0; ct < 4; ++ct)
#pragma unroll
    for (int r = 0; r < 4; ++r)
      ob[(g * 4 + r) * DV + ct * 16 + m] = acc[ct][r] * invz[r];
}

}  // namespace

extern "C" void kernel_launch(void* const* d_in, const int* in_sizes, int n_in,
                              void* d_out, int out_size, void* d_ws, size_t ws_size,
                              hipStream_t stream) {
  const float* Q = (const float*)d_in[0];
  const float* K = (const float*)d_in[1];
  const float* V = (const float*)d_in[2];
  float* Out = (float*)d_out;

  if (ws_size >= WS_NEED && d_ws != nullptr) {
    u16* khf  = (u16*)((char*)d_ws + KHF_OFF);
    u16* vthf = (u16*)((char*)d_ws + VTHF_OFF);

    hipLaunchKernelGGL(pack_kv, dim3(4096), dim3(256), 0, stream, K, V, khf, vthf);
    hipLaunchKernelGGL(taylor_attn_v12, dim3(2048), dim3(256), 0, stream,
                       Q, khf, vthf, Out);
  } else {
    hipLaunchKernelGGL(taylor_attn_fb, dim3(1024), dim3(256), 0, stream,
                       Q, K, V, Out);
  }
}

// Round 14
// 68.685 us; speedup vs baseline: 4.6798x; 1.3630x over previous
//
#include <hip/hip_runtime.h>
#include <hip/hip_bf16.h>

// Taylor attention v13: L1-sharing restructure. Block = 4 waves owning q-strips
// 4t..4t+3 (128 q-rows), ALL waves march the SAME kt sequence with plain global
// loads -> the 4 waves hit the same K/V cache lines each step (L1 serves 3/4).
// No barriers, no LDS, direct per-wave store. 512 blocks heavy-first.
// Step math identical to v10b: fp16 QK^T (32x32x16), packed-fp16 Horner poly,
// half2 regs are PV A-frag pairs (permlane32_swap), fp16 V, pk-tree Z.

typedef __attribute__((ext_vector_type(8))) short bf16x8;
typedef __attribute__((ext_vector_type(8))) _Float16 f16x8;
typedef __attribute__((ext_vector_type(2))) _Float16 h2;
typedef __attribute__((ext_vector_type(2))) __fp16 fp16x2b;
typedef __attribute__((ext_vector_type(4))) float f32x4;
typedef __attribute__((ext_vector_type(16))) float f32x16;
typedef unsigned int u32;
typedef unsigned short u16;

namespace {

constexpr int T_SEQ = 2048;
constexpr int DK    = 32;
constexpr int DV    = 64;
constexpr int NBH   = 32;

// w = ((C3*s + C2)*s + C1)*s + 1  with s = raw dot (1/sqrt(32) folded in)
constexpr float C1 = 0.17677669529663687f;   // c
constexpr float C2 = 0.015625f;              // c^2/2 (exact)
constexpr float C3 = 9.2071195e-4f;          // c^3/6

// workspace layout (bytes): Khf (fp16) 4MiB | Vthf (fp16, transposed) 8MiB
constexpr size_t KHF_OFF  = 0;
constexpr size_t VTHF_OFF = (size_t)NBH * T_SEQ * DK * 2;             //  4 MiB
constexpr size_t WS_NEED  = VTHF_OFF + (size_t)NBH * DV * T_SEQ * 2;  // 12 MiB

__device__ __forceinline__ u32 pack_hi2(float f0, float f1) {
  return (__float_as_uint(f0) >> 16) | (__float_as_uint(f1) & 0xffff0000u);
}
__device__ __forceinline__ float trunc_bf(float f) {
  return __uint_as_float(__float_as_uint(f) & 0xffff0000u);
}
__device__ __forceinline__ u16 f2h(float f) {
  union { _Float16 h; u16 u; } c;
  c.h = (_Float16)f;             // RNE
  return c.u;
}
// Swap a.lanes[32:63] <-> b.lanes[0:31].
__device__ __forceinline__ void permswap(u32& a, u32& b) {
  asm volatile("v_permlane32_swap_b32 %0, %1" : "+v"(a), "+v"(b));
}

// ---------------- pack kernel (K -> fp16; V^T -> fp16) ----------------

__global__ void pack_kv(const float* __restrict__ Kg, const float* __restrict__ Vg,
                        u16* __restrict__ Khf, u16* __restrict__ Vthf) {
  __shared__ float tile[DV][33];
  const int bid = blockIdx.x;
  const int t   = threadIdx.x;
  if (bid < 2048) {  // ---- K: elementwise fp16 convert
    size_t i = ((size_t)bid * 256 + t) * 4;
    float4 f = *(const float4*)(Kg + i);
    ushort4 h;
    h.x = f2h(f.x); h.y = f2h(f.y); h.z = f2h(f.z); h.w = f2h(f.w);
    *(ushort4*)(Khf + i) = h;
  } else {           // ---- V: transpose 32k x 64c tiles, fp16
    const int vb = bid - 2048;
    const int bh = vb >> 6;
    const int k0 = (vb & 63) * 32;
    {
      const int kl = t >> 3, c0 = (t & 7) * 8;
      const float* src = Vg + ((size_t)bh * T_SEQ + k0 + kl) * DV + c0;
      float4 a = *(const float4*)src;
      float4 b = *(const float4*)(src + 4);
      tile[c0 + 0][kl] = a.x; tile[c0 + 1][kl] = a.y;
      tile[c0 + 2][kl] = a.z; tile[c0 + 3][kl] = a.w;
      tile[c0 + 4][kl] = b.x; tile[c0 + 5][kl] = b.y;
      tile[c0 + 6][kl] = b.z; tile[c0 + 7][kl] = b.w;
    }
    __syncthreads();
    {
      const int cl = t >> 2, k8 = (t & 3) * 8;
      ushort4 h0, h1;
      h0.x = f2h(tile[cl][k8 + 0]); h0.y = f2h(tile[cl][k8 + 1]);
      h0.z = f2h(tile[cl][k8 + 2]); h0.w = f2h(tile[cl][k8 + 3]);
      h1.x = f2h(tile[cl][k8 + 4]); h1.y = f2h(tile[cl][k8 + 5]);
      h1.z = f2h(tile[cl][k8 + 6]); h1.w = f2h(tile[cl][k8 + 7]);
      size_t off = ((size_t)(bh * DV + cl)) * T_SEQ + k0 + k8;
      *(ushort4*)(Vthf + off)     = h0;
      *(ushort4*)(Vthf + off + 4) = h1;
    }
  }
}

// ---------------- main kernel (v13) ----------------

__global__ __launch_bounds__(256, 4)
void taylor_attn_v13(const float* __restrict__ Qg, const u16* __restrict__ Khf,
                     const u16* __restrict__ Vthf, float* __restrict__ Outg) {
  const int tid = threadIdx.x;
  const int l   = tid & 63;
  const int w   = tid >> 6;
  const int cq  = l & 31;
  const int hi  = l >> 5;

  // decode: 512 blocks = 16 q-tiles (heavy first) x 32 bh.
  // XCD x = bid&7 serves bh in {4x..4x+3} (K/V L2-resident).
  const int bid = blockIdx.x;
  const int t_  = 15 - (bid >> 5);           // q-tile 15..0, heavy first
  const int bh  = (bid & 7) * 4 + ((bid >> 3) & 3);
  const int sw  = 4 * t_ + w;                // this wave's 32-row strip
  const int q0w = sw * 32;

  const u16* kq = Khf + (size_t)bh * T_SEQ * DK + (size_t)cq * DK + hi * 8;
  const u16* vq = Vthf + (size_t)bh * DV * T_SEQ + (size_t)cq * T_SEQ + hi * 8;

  const h2 C3h = {(_Float16)C3, (_Float16)C3};
  const h2 C2h = {(_Float16)C2, (_Float16)C2};
  const h2 C1h = {(_Float16)C1, (_Float16)C1};
  const h2 ONEh = {(_Float16)1.0f, (_Float16)1.0f};

  f32x16 ZERO;
#pragma unroll
  for (int r = 0; r < 16; ++r) ZERO[r] = 0.f;

  // ---- Q B-fragments, fp16 RNE (col=q=cq, d = t*16 + hi*8 + j)
  f16x8 qf[2];
#pragma unroll
  for (int t = 0; t < 2; ++t) {
    const float* qp = Qg + ((size_t)bh * T_SEQ + q0w + cq) * DK + t * 16 + hi * 8;
    float4 a = *(const float4*)qp;
    float4 b = *(const float4*)(qp + 4);
    f16x8 v;
    v[0] = (_Float16)a.x; v[1] = (_Float16)a.y;
    v[2] = (_Float16)a.z; v[3] = (_Float16)a.w;
    v[4] = (_Float16)b.x; v[5] = (_Float16)b.y;
    v[6] = (_Float16)b.z; v[7] = (_Float16)b.w;
    qf[t] = v;
  }

  f32x16 acc0 = ZERO, acc1 = ZERO;
  float zacc = 0.f;

  auto LOADK = [&](f16x8* kf, int kt) {
    const u16* kp = kq + (size_t)kt * 1024;
    kf[0] = *(const f16x8*)kp;
    kf[1] = *(const f16x8*)(kp + 16);
  };
  auto LOADV = [&](f16x8* vf, int kt) {
#pragma unroll
    for (int ct = 0; ct < 2; ++ct)
#pragma unroll
      for (int t = 0; t < 2; ++t)
        vf[ct * 2 + t] = *(const f16x8*)(
            vq + (size_t)ct * 32 * T_SEQ + kt * 32 + t * 16);
  };
  auto STEP = [&](const f16x8* kf, const f16x8* vf, bool diag) {
    f32x16 d = __builtin_amdgcn_mfma_f32_32x32x16_f16(kf[0], qf[0], ZERO, 0, 0, 0);
    d = __builtin_amdgcn_mfma_f32_32x32x16_f16(kf[1], qf[1], d, 0, 0, 0);

    union cvu { fp16x2b p; h2 h; u32 u; };
    cvu wv[8];
#pragma unroll
    for (int j = 0; j < 8; ++j) {
      cvu c;
      c.p = __builtin_amdgcn_cvt_pkrtz(d[2 * j], d[2 * j + 1]);
      h2 sc = c.h;
      h2 t_h = sc * C3h + C2h;
      t_h    = sc * t_h + C1h;
      wv[j].h = sc * t_h + ONEh;
    }
    if (diag) {
#pragma unroll
      for (int j = 0; j < 8; ++j) {
        const int r0  = 2 * j;
        const int kre = (r0 & 3) + 8 * (r0 >> 2) + 4 * hi;
        u32 msk = ((kre <= cq) ? 0xffffu : 0u) |
                  ((kre + 1 <= cq) ? 0xffff0000u : 0u);
        wv[j].u &= msk;
      }
    }
    {
      h2 zs = ((wv[0].h + wv[1].h) + (wv[2].h + wv[3].h)) +
              ((wv[4].h + wv[5].h) + (wv[6].h + wv[7].h));
      zacc += (float)zs[0] + (float)zs[1];
    }
    union { f16x8 v; u32 u[4]; } WH[2];
#pragma unroll
    for (int t = 0; t < 2; ++t) {
      u32 p0 = wv[4 * t + 0].u, p1 = wv[4 * t + 1].u;
      u32 p2 = wv[4 * t + 2].u, p3 = wv[4 * t + 3].u;
      permswap(p0, p2); permswap(p1, p3);
      WH[t].u[0] = p0; WH[t].u[1] = p1; WH[t].u[2] = p2; WH[t].u[3] = p3;
    }
    acc0 = __builtin_amdgcn_mfma_f32_32x32x16_f16(WH[0].v, vf[0], acc0, 0, 0, 0);
    acc0 = __builtin_amdgcn_mfma_f32_32x32x16_f16(WH[1].v, vf[1], acc0, 0, 0, 0);
    acc1 = __builtin_amdgcn_mfma_f32_32x32x16_f16(WH[0].v, vf[2], acc1, 0, 0, 0);
    acc1 = __builtin_amdgcn_mfma_f32_32x32x16_f16(WH[1].v, vf[3], acc1, 0, 0, 0);
  };

  // ---- pipelined main loop over kt = 0..sw-1 (mask-free), stride 1:
  //      ALL 4 waves march the same kt -> shared L1 lines. K dbuf, V early.
  {
    int kt = 0;
    if (sw > 0) {
      f16x8 kA[2], kB[2];
      LOADK(kA, 0);
      while (true) {
        int kn = kt + 1;
        if (kn < sw) {
          LOADK(kB, kn);
          f16x8 vf[4]; LOADV(vf, kt);
          STEP(kA, vf, false);
          kt = kn;
        } else {
          f16x8 vf[4]; LOADV(vf, kt);
          STEP(kA, vf, false);
          break;
        }
        kn = kt + 1;
        if (kn < sw) {
          LOADK(kA, kn);
          f16x8 vf[4]; LOADV(vf, kt);
          STEP(kB, vf, false);
          kt = kn;
        } else {
          f16x8 vf[4]; LOADV(vf, kt);
          STEP(kB, vf, false);
          break;
        }
      }
    }
  }
  // ---- diagonal step (every wave, masked)
  {
    f16x8 kD[2]; LOADK(kD, sw);
    f16x8 vD[4]; LOADV(vD, sw);
    STEP(kD, vD, true);
  }

  // ---- Z fold across lane halves (lane l, l^32 share q=cq); direct store
  float zt = zacc + __shfl_xor(zacc, 32);
  float iz = 1.0f / zt;                  // inv Z for q=cq (all lanes)

  float* ob = Outg + ((size_t)bh * T_SEQ + q0w) * DV;
#pragma unroll
  for (int r = 0; r < 16; ++r) {
    const int qr = (r & 3) + 8 * (r >> 2) + 4 * hi;
    float izr = __shfl(iz, qr);          // z of row qr lives in lane qr
    ob[(size_t)qr * DV + cq]      = acc0[r] * izr;
    ob[(size_t)qr * DV + 32 + cq] = acc1[r] * izr;
  }
}

// ---------------- fallback (no workspace): v2 staged-LDS kernel ----------------

constexpr int QT_FB = 64;
constexpr int KT_FB = 32;
constexpr int LDSW  = 40;
constexpr float SCALE = 0.17677669529663687f;

__global__ __launch_bounds__(256, 4)
void taylor_attn_fb(const float* __restrict__ Qg, const float* __restrict__ Kg,
                    const float* __restrict__ Vg, float* __restrict__ Outg) {
  __shared__ __align__(16) unsigned short Qhi[QT_FB * LDSW], Qlo[QT_FB * LDSW];
  __shared__ __align__(16) unsigned short Khi_[KT_FB * LDSW], Klo_[KT_FB * LDSW];
  __shared__ __align__(16) unsigned short Vthi_[DV * LDSW], Vtlo_[DV * LDSW];
  __shared__ __align__(16) unsigned Wp[4][16 * 32];

  const int tid  = threadIdx.x;
  const int lane = tid & 63;
  const int wid  = tid >> 6;
  const int m    = lane & 15;
  const int g    = lane >> 4;

  const int bid = blockIdx.x;
  const int v   = bid >> 3;
  const int bh  = (bid & 7) * 4 + (v >> 5);
  const int qt  = 31 - (v & 31);
  const int q0  = qt * QT_FB;

  const float* Qbase = Qg + ((size_t)bh * T_SEQ + q0) * DK;
  const float* Kbase = Kg + (size_t)bh * T_SEQ * DK;
  const float* Vbase = Vg + (size_t)bh * T_SEQ * DV;

#pragma unroll
  for (int p = 0; p < 2; ++p) {
    int e = tid + p * 256, row = e >> 3, c4 = (e & 7) * 4;
    float4 f = *(const float4*)(Qbase + row * DK + c4);
    uint2 h, l;
    h.x = pack_hi2(f.x, f.y); h.y = pack_hi2(f.z, f.w);
    l.x = pack_hi2(f.x - trunc_bf(f.x), f.y - trunc_bf(f.y));
    l.y = pack_hi2(f.z - trunc_bf(f.z), f.w - trunc_bf(f.w));
    *(uint2*)&Qhi[row * LDSW + c4] = h;
    *(uint2*)&Qlo[row * LDSW + c4] = l;
  }
  __syncthreads();

  const int wq = wid * 16;
  const bf16x8 qhi = *(const bf16x8*)&Qhi[(wq + m) * LDSW + g * 8];
  const bf16x8 qlo = *(const bf16x8*)&Qlo[(wq + m) * LDSW + g * 8];

  f32x4 acc[4];
#pragma unroll
  for (int ct = 0; ct < 4; ++ct) acc[ct] = f32x4{0.f, 0.f, 0.f, 0.f};
  float zacc[4] = {0.f, 0.f, 0.f, 0.f};

  const int q_lane0 = q0 + wq + g * 4;
  const int q_wave_max = q0 + wq + 15;

  const int nkt = (q0 + QT_FB) / KT_FB;
  for (int kt = 0; kt < nkt; ++kt) {
    const int k0 = kt * KT_FB;
    __syncthreads();
    {
      int row = tid >> 3, c4 = (tid & 7) * 4;
      float4 f = *(const float4*)(Kbase + (size_t)(k0 + row) * DK + c4);
      uint2 h, l;
      h.x = pack_hi2(f.x, f.y); h.y = pack_hi2(f.z, f.w);
      l.x = pack_hi2(f.x - trunc_bf(f.x), f.y - trunc_bf(f.y));
      l.y = pack_hi2(f.z - trunc_bf(f.z), f.w - trunc_bf(f.w));
      *(uint2*)&Khi_[row * LDSW + c4] = h;
      *(uint2*)&Klo_[row * LDSW + c4] = l;
    }
    {
      int kk = (tid & 15) * 2, c4 = (tid >> 4) * 4;
      const float* vp = Vbase + (size_t)(k0 + kk) * DV + c4;
      float4 a = *(const float4*)vp;
      float4 b = *(const float4*)(vp + DV);
      float af[4] = {a.x, a.y, a.z, a.w};
      float bf_[4] = {b.x, b.y, b.z, b.w};
#pragma unroll
      for (int jj = 0; jj < 4; ++jj) {
        *(unsigned*)&Vthi_[(c4 + jj) * LDSW + kk] = pack_hi2(af[jj], bf_[jj]);
        *(unsigned*)&Vtlo_[(c4 + jj) * LDSW + kk] =
            pack_hi2(af[jj] - trunc_bf(af[jj]), bf_[jj] - trunc_bf(bf_[jj]));
      }
    }
    __syncthreads();

    if (k0 > q_wave_max) continue;

#pragma unroll
    for (int k16 = 0; k16 < 2; ++k16) {
      const int kcol0 = k16 * 16;
      bf16x8 khi = *(const bf16x8*)&Khi_[(kcol0 + m) * LDSW + g * 8];
      bf16x8 klo = *(const bf16x8*)&Klo_[(kcol0 + m) * LDSW + g * 8];
      f32x4 sc = {0.f, 0.f, 0.f, 0.f};
      sc = __builtin_amdgcn_mfma_f32_16x16x32_bf16(qhi, khi, sc, 0, 0, 0);
      sc = __builtin_amdgcn_mfma_f32_16x16x32_bf16(qhi, klo, sc, 0, 0, 0);
      sc = __builtin_amdgcn_mfma_f32_16x16x32_bf16(qlo, khi, sc, 0, 0, 0);
      const int k_abs = k0 + kcol0 + m;
      const int kcol  = kcol0 + m;
#pragma unroll
      for (int r = 0; r < 4; ++r) {
        float x  = sc[r] * SCALE;
        float a3 = __builtin_fmaf(x, 0.3333333333333333f, 1.0f);
        float a2 = __builtin_fmaf(x * 0.5f, a3, 1.0f);
        float wvv = __builtin_fmaf(x, a2, 1.0f);
        wvv = (k_abs <= q_lane0 + r) ? wvv : 0.0f;
        zacc[r] += wvv;
        float wl = wvv - trunc_bf(wvv);
        unsigned packed = (__float_as_uint(wvv) >> 16) |
                          (__float_as_uint(wl) & 0xffff0000u);
        const int q = g * 4 + r;
        Wp[wid][q * 32 + (((kcol >> 2) ^ (q & 7)) << 2) + (kcol & 3)] = packed;
      }
    }

    uint4 pa = *(const uint4*)&Wp[wid][m * 32 + (((2 * g) ^ (m & 7)) << 2)];
    uint4 pb = *(const uint4*)&Wp[wid][m * 32 + (((2 * g + 1) ^ (m & 7)) << 2)];
    union { bf16x8 v; unsigned u[4]; } WH, WL;
    WH.u[0] = (pa.x & 0xffffu) | (pa.y << 16);
    WH.u[1] = (pa.z & 0xffffu) | (pa.w << 16);
    WH.u[2] = (pb.x & 0xffffu) | (pb.y << 16);
    WH.u[3] = (pb.z & 0xffffu) | (pb.w << 16);
    WL.u[0] = (pa.x >> 16) | (pa.y & 0xffff0000u);
    WL.u[1] = (pa.z >> 16) | (pa.w & 0xffff0000u);
    WL.u[2] = (pb.x >> 16) | (pb.y & 0xffff0000u);
    WL.u[3] = (pb.z >> 16) | (pb.w & 0xffff0000u);

#pragma unroll
    for (int ct = 0; ct < 4; ++ct) {
      bf16x8 vhi = *(const bf16x8*)&Vthi_[(ct * 16 + m) * LDSW + g * 8];
      bf16x8 vlo = *(const bf16x8*)&Vtlo_[(ct * 16 + m) * LDSW + g * 8];
      acc[ct] = __builtin_amdgcn_mfma_f32_16x16x32_bf16(WH.v, vhi, acc[ct], 0, 0, 0);
      acc[ct] = __builtin_amdgcn_mfma_f32_16x16x32_bf16(WH.v, vlo, acc[ct], 0, 0, 0);
      acc[ct] = __builtin_amdgcn_mfma_f32_16x16x32_bf16(WL.v, vhi, acc[ct], 0, 0, 0);
    }
  }

  float invz[4];
#pragma unroll
  for (int r = 0; r < 4; ++r) {
    float z = zacc[r];
    z += __shfl_xor(z, 1); z += __shfl_xor(z, 2);
    z += __shfl_xor(z, 4); z += __shfl_xor(z, 8);
    invz[r] = 1.0f / z;
  }

  float* ob = Outg + ((size_t)bh * T_SEQ + (q0 + wq)) * DV;
#pragma unroll
  for (int ct = 0; ct < 4; ++ct)
#pragma unroll
    for (int r = 0; r < 4; ++r)
      ob[(g * 4 + r) * DV + ct * 16 + m] = acc[ct][r] * invz[r];
}

}  // namespace

extern "C" void kernel_launch(void* const* d_in, const int* in_sizes, int n_in,
                              void* d_out, int out_size, void* d_ws, size_t ws_size,
                              hipStream_t stream) {
  const float* Q = (const float*)d_in[0];
  const float* K = (const float*)d_in[1];
  const float* V = (const float*)d_in[2];
  float* Out = (float*)d_out;

  if (ws_size >= WS_NEED && d_ws != nullptr) {
    u16* khf  = (u16*)((char*)d_ws + KHF_OFF);
    u16* vthf = (u16*)((char*)d_ws + VTHF_OFF);

    hipLaunchKernelGGL(pack_kv, dim3(4096), dim3(256), 0, stream, K, V, khf, vthf);
    hipLaunchKernelGGL(taylor_attn_v13, dim3(512), dim3(256), 0, stream,
                       Q, khf, vthf, Out);
  } else {
    hipLaunchKernelGGL(taylor_attn_fb, dim3(1024), dim3(256), 0, stream,
                       Q, K, V, Out);
  }
}